// Round 10
// baseline (279.207 us; speedup 1.0000x reference)
//
#include <hip/hip_runtime.h>
#include <hip/hip_bf16.h>

// Problem constants
#define BATCH   256
#define NP      196
#define HIDDEN  1024
#define ATT     512
#define M_TOTAL (BATCH * NP)   // 50176 rows
#define BM 64
#define MT_TILES (M_TOTAL / BM)   // 784 blocks

typedef __attribute__((ext_vector_type(8))) short bf16x8v;  // 8 bf16 = 4 VGPR
typedef __attribute__((ext_vector_type(4))) float f32x4;

// f32 -> bf16 RNE (cold path)
__device__ inline unsigned short f2bf(float x) {
    unsigned int u = __float_as_uint(x);
    u += 0x7fffu + ((u >> 16) & 1u);
    return (unsigned short)(u >> 16);
}

// packed f32 pair -> 2x bf16 via v_cvt_pk_bf16_f32 (no builtin on gfx950)
__device__ __forceinline__ unsigned int pk2bf(float lo, float hi) {
    unsigned int r;
    asm("v_cvt_pk_bf16_f32 %0, %1, %2" : "=v"(r) : "v"(lo), "v"(hi));
    return r;
}

__device__ inline float fast_tanh(float x) {
    float e = __expf(2.0f * x);
    return 1.0f - 2.0f / (e + 1.0f);
}

// async global->LDS, 16 bytes per lane.
__device__ __forceinline__ void glds16(const void* gsrc, void* ldst) {
    __builtin_amdgcn_global_load_lds(
        (const __attribute__((address_space(1))) unsigned int*)gsrc,
        (__attribute__((address_space(3))) unsigned int*)ldst,
        16, 0, 0);
}

// ---------------------------------------------------------------------------
// K0: W_cnn (f32 [1024][512]) -> bf16 B images for K2.
// Wt[h 2][kt 32][16KB image]; image byte = col*64 + slot*16 (col 0..255 local).
// Slot holds k-chunk c = slot ^ ((col>>1)&3); k = kt*32 + c*8 + j.
// glds copies each image linearly; the LDS read applies the same XOR.
// ---------------------------------------------------------------------------
__global__ void k0_arrange(const float* __restrict__ Wc, unsigned short* __restrict__ Wt) {
    int g = blockIdx.x * 256 + threadIdx.x;   // 65536 slots of 8 bf16
    int h    = g >> 15;
    int kt   = (g >> 10) & 31;
    int col  = (g >> 2) & 255;
    int slot = g & 3;
    int c    = slot ^ ((col >> 1) & 3);
    int kb   = kt * 32 + c * 8;
    int colg = h * 256 + col;
    unsigned short v[8];
#pragma unroll
    for (int j = 0; j < 8; ++j) v[j] = f2bf(Wc[(size_t)(kb + j) * ATT + colg]);
    uint4 pk;
    pk.x = (unsigned int)v[0] | ((unsigned int)v[1] << 16);
    pk.y = (unsigned int)v[2] | ((unsigned int)v[3] << 16);
    pk.z = (unsigned int)v[4] | ((unsigned int)v[5] << 16);
    pk.w = (unsigned int)v[6] | ((unsigned int)v[7] << 16);
    *(uint4*)(Wt + (size_t)g * 8) = pk;
}

// ---------------------------------------------------------------------------
// K1: dec_out = decoder_out @ W_dec ; stw = st @ W_sen   (f32)
// ---------------------------------------------------------------------------
__global__ void k1_small(const float* __restrict__ dec_in, const float* __restrict__ st,
                         const float* __restrict__ Wdec,  const float* __restrict__ Wsen,
                         float* __restrict__ dec_out, float* __restrict__ stw) {
    const float* X = blockIdx.z ? st   : dec_in;
    const float* W = blockIdx.z ? Wsen : Wdec;
    float*       O = blockIdx.z ? stw  : dec_out;
    int ci = threadIdx.x & 31;
    int c0 = blockIdx.x * 128 + ci * 4;
    int b  = blockIdx.y * 8 + (threadIdx.x >> 5);
    const float* x = X + (size_t)b * HIDDEN;
    float4 acc = {0.f, 0.f, 0.f, 0.f};
    for (int k = 0; k < HIDDEN; k += 4) {
#pragma unroll
        for (int kk = 0; kk < 4; ++kk) {
            float4 w = *(const float4*)(W + (size_t)(k + kk) * ATT + c0);
            float a = x[k + kk];
            acc.x += a * w.x; acc.y += a * w.y; acc.z += a * w.z; acc.w += a * w.w;
        }
    }
    *(float4*)(O + (size_t)b * ATT + c0) = acc;
}

// ---------------------------------------------------------------------------
// K2: fused  zt[r] = sum_a tanh((A@Wc)[r,a] + dec[b,a]) * Watt[a]
// Block = 64 contiguous rows (256 KB f32, read ONCE, fully coalesced),
// converted once into a persistent 128 KB bf16 LDS A-image (XOR-swizzled).
// Inner loop: 2 col-halves x 32 K-steps; stage ONE 16 KB B image per step
// (4 contiguous glds16/thread from pre-swizzled Wt), double-buffered, one
// vmcnt(0)+barrier per step (B latency covered by previous compute phase).
// 256 thr / 4 waves, wave = 64x64 (af[4]+bfr[4] -> 16 MFMA per step).
// Epilogues per half keep row sums in regs; zred aliased into the B region.
// ---------------------------------------------------------------------------
__global__ void __launch_bounds__(256, 1)
k2_fused(const float* __restrict__ A, const unsigned short* __restrict__ Wt,
         const float* __restrict__ dec, const float* __restrict__ Watt,
         float* __restrict__ zt) {
    __shared__ __align__(16) char lds[163840];   // [A 131072][B0 16384][B1 16384]
    char* B0 = lds + 131072;
    char* B1 = lds + 147456;
    float* zred = (float*)(lds + 131072);        // aliased; used after B0's last read

    const int tid = threadIdx.x;
    const int wv = tid >> 6;       // wave 0..3 = column-wave within the half
    const int l  = tid & 63;
    const int lg = l >> 4, ll = l & 15;

    // XCD-bijective swizzle: 784 = 8 XCDs x 98 (Wt stays hot in every XCD L2).
    const int bid = (int)blockIdx.x;
    const int mt = (bid & 7) * 98 + (bid >> 3);
    const int r0 = mt * BM;

    f32x4 acc[4][4];
#pragma unroll
    for (int m = 0; m < 4; ++m)
#pragma unroll
        for (int n = 0; n < 4; ++n) acc[m][n] = (f32x4){0.f, 0.f, 0.f, 0.f};
    float srow[4][4];
#pragma unroll
    for (int m = 0; m < 4; ++m)
#pragma unroll
        for (int j = 0; j < 4; ++j) srow[m][j] = 0.f;

    const float* Asrc = A + (size_t)r0 * HIDDEN;

#define BSTAGE(h, kt, Bb) do {                                                 \
    const char* _s = (const char*)Wt + (size_t)(h) * 524288 +                  \
                     (size_t)(kt) * 16384 + tid * 16;                          \
    glds16(_s,          (Bb) + tid * 16);                                      \
    glds16(_s + 4096,   (Bb) + 4096  + tid * 16);                              \
    glds16(_s + 8192,   (Bb) + 8192  + tid * 16);                              \
    glds16(_s + 12288,  (Bb) + 12288 + tid * 16);                              \
} while (0)

#define COMPUTE(t, Bb) do {                                                    \
    bf16x8v af[4], bfr[4];                                                     \
    _Pragma("unroll")                                                          \
    for (int m = 0; m < 4; ++m) {                                              \
        int row = m * 16 + ll;                                                 \
        af[m] = *(const bf16x8v*)(lds + row * 2048 +                           \
                 (((t) * 64 + (lg << 4)) ^ ((row & 7) << 4)));                 \
    }                                                                          \
    _Pragma("unroll")                                                          \
    for (int n = 0; n < 4; ++n) {                                              \
        int col = wv * 64 + n * 16 + ll;                                       \
        bfr[n] = *(const bf16x8v*)((Bb) + col * 64 +                           \
                 (((lg << 4)) ^ (((col >> 1) & 3) << 4)));                     \
    }                                                                          \
    __builtin_amdgcn_s_setprio(1);                                             \
    _Pragma("unroll")                                                          \
    for (int m = 0; m < 4; ++m)                                                \
        _Pragma("unroll")                                                      \
        for (int n = 0; n < 4; ++n)                                            \
            acc[m][n] = __builtin_amdgcn_mfma_f32_16x16x32_bf16(               \
                af[m], bfr[n], acc[m][n], 0, 0, 0);                            \
    __builtin_amdgcn_s_setprio(0);                                             \
} while (0)

#define SYNCV do {                                                             \
    asm volatile("s_waitcnt vmcnt(0)" ::: "memory");                           \
    __builtin_amdgcn_s_barrier();                                              \
} while (0)

    // ---- Prologue: B(0,0) async + A-stage (once, fully coalesced) ----
    BSTAGE(0, 0, B0);
    // 64 rows x 4 KB = 256 KB; thread handles k-chunk (tid*16B) of every row.
#pragma unroll
    for (int bb = 0; bb < 4; ++bb) {
        float4 tt[16];
#pragma unroll
        for (int i2 = 0; i2 < 16; ++i2)
            tt[i2] = *(const float4*)(Asrc + ((size_t)(bb * 16 + i2) * 256 + tid) * 4);
#pragma unroll
        for (int i2 = 0; i2 < 16; ++i2) {
            int i = bb * 16 + i2;
            uint2 u;
            u.x = pk2bf(tt[i2].x, tt[i2].y);
            u.y = pk2bf(tt[i2].z, tt[i2].w);
            *(uint2*)(lds + i * 2048 + ((tid * 8) ^ ((i & 7) << 4))) = u;
        }
    }
    asm volatile("s_waitcnt vmcnt(0) lgkmcnt(0)" ::: "memory");
    __builtin_amdgcn_s_barrier();

    // ---- Two column-halves, 32 K-steps each ----
#pragma unroll 1
    for (int h = 0; h < 2; ++h) {
        // entry: B(h,0) resident in B0, drained.
        for (int tp = 0; tp < 15; ++tp) {
            const int t = tp * 2;
            BSTAGE(h, t + 1, B1); COMPUTE(t, B0); SYNCV;
            BSTAGE(h, t + 2, B0); COMPUTE(t + 1, B1); SYNCV;
        }
        BSTAGE(h, 31, B1); COMPUTE(30, B0); SYNCV;
        if (h == 0) { BSTAGE(1, 0, B0); COMPUTE(31, B1); SYNCV; }
        else        { COMPUTE(31, B1); }

        // Epilogue for this half: tanh + dec add + Watt dot, row-sum in regs.
        // C frag layout (m89-verified): row = lg*4 + j, col = ll.
        const int clocal = wv * 64 + ll;
        const int cg = h * 256 + clocal;
        float watt[4];
#pragma unroll
        for (int n = 0; n < 4; ++n) watt[n] = Watt[cg + n * 16];
#pragma unroll
        for (int m = 0; m < 4; ++m) {
#pragma unroll
            for (int j = 0; j < 4; ++j) {
                int rowg = r0 + m * 16 + lg * 4 + j;
                int b = rowg / NP;
                const float* db = dec + (size_t)b * ATT + cg;
                float s = 0.f;
#pragma unroll
                for (int n = 0; n < 4; ++n)
                    s += fast_tanh(acc[m][n][j] + db[n * 16]) * watt[n];
                s += __shfl_xor(s, 1);
                s += __shfl_xor(s, 2);
                s += __shfl_xor(s, 4);
                s += __shfl_xor(s, 8);
                srow[m][j] += s;      // valid on ll==0 lanes
            }
        }
        if (h == 0) {
#pragma unroll
            for (int m = 0; m < 4; ++m)
#pragma unroll
                for (int n = 0; n < 4; ++n) acc[m][n] = (f32x4){0.f, 0.f, 0.f, 0.f};
        }
    }

#undef BSTAGE
#undef COMPUTE
#undef SYNCV

    // ---- Final cross-wave reduction (zred aliases B0; B0's last read was
    // step t=30 of half 1, retired before that step's barrier). ----
    __builtin_amdgcn_s_barrier();
    if (ll == 0) {
#pragma unroll
        for (int m = 0; m < 4; ++m)
#pragma unroll
            for (int j = 0; j < 4; ++j)
                zred[(m * 16 + lg * 4 + j) * 4 + wv] = srow[m][j];
    }
    __syncthreads();
    if (tid < 64) {
        zt[r0 + tid] = zred[tid * 4] + zred[tid * 4 + 1]
                     + zred[tid * 4 + 2] + zred[tid * 4 + 3];
    }
}

// ---------------------------------------------------------------------------
// K3: per-b: out = tanh(dec+stw)@Watt ; alpha = softmax(zt) ; beta.
// ---------------------------------------------------------------------------
__global__ void k3_softmax(const float* __restrict__ dec, const float* __restrict__ stw,
                           const float* __restrict__ Watt, const float* __restrict__ zt,
                           float* __restrict__ out, float* __restrict__ beta_ws) {
    int b = blockIdx.x;
    int t = threadIdx.x;
    __shared__ float red[256];

    float p = 0.f;
#pragma unroll
    for (int c = t; c < ATT; c += 256)
        p += fast_tanh(dec[(size_t)b * ATT + c] + stw[(size_t)b * ATT + c]) * Watt[c];
    red[t] = p;
    __syncthreads();
    for (int s = 128; s > 0; s >>= 1) { if (t < s) red[t] += red[t + s]; __syncthreads(); }
    float outv = red[0];
    __syncthreads();

    float z = (t < NP) ? zt[b * NP + t] : -1e30f;
    red[t] = z;
    __syncthreads();
    for (int s = 128; s > 0; s >>= 1) { if (t < s) red[t] = fmaxf(red[t], red[t + s]); __syncthreads(); }
    float m1 = red[0];
    __syncthreads();

    float e = (t < NP) ? __expf(z - m1) : 0.f;
    red[t] = e;
    __syncthreads();
    for (int s = 128; s > 0; s >>= 1) { if (t < s) red[t] += red[t + s]; __syncthreads(); }
    float s1 = red[0];

    if (t < NP) out[b * NP + t] = e / s1;                       // alpha_t

    if (t == 0) {
        float m2 = fmaxf(m1, outv);
        float s2 = s1 * __expf(m1 - m2) + __expf(outv - m2);
        float beta = __expf(outv - m2) / s2;
        out[M_TOTAL + b] = beta;                                 // beta_t
        beta_ws[b] = beta;
    }
}

// ---------------------------------------------------------------------------
// K4: ct partials. grid (4 p-quarters, 256 b), block 256 (thread = 4 h).
// ---------------------------------------------------------------------------
__global__ void k4_ct(const float* __restrict__ spatial, const float* __restrict__ alpha,
                      float* __restrict__ ctp) {
    int q = blockIdx.x;
    int b = blockIdx.y;
    int t = threadIdx.x;
    __shared__ float al[49];
    if (t < 49) al[t] = alpha[b * NP + q * 49 + t];
    __syncthreads();
    const float* sp = spatial + (size_t)b * NP * HIDDEN + (size_t)q * 49 * HIDDEN + t * 4;
    float4 acc = {0.f, 0.f, 0.f, 0.f};
#pragma unroll 7
    for (int p = 0; p < 49; ++p) {
        float4 v = *(const float4*)(sp + (size_t)p * HIDDEN);
        float a = al[p];
        acc.x += a * v.x; acc.y += a * v.y; acc.z += a * v.z; acc.w += a * v.w;
    }
    *(float4*)(ctp + ((size_t)q * BATCH + b) * HIDDEN + t * 4) = acc;
}

// ---------------------------------------------------------------------------
// K5: c_hat = beta*st + (1-beta)*ct  (sums the 4 ct partials)
// ---------------------------------------------------------------------------
__global__ void k5_chat(const float* __restrict__ st, const float* __restrict__ ctp,
                        const float* __restrict__ beta, float* __restrict__ chat) {
    int g = blockIdx.x * 256 + threadIdx.x;
    int b = g >> 8;
    int h0 = (g & 255) * 4;
    float be = beta[b];
    float4 s = *(const float4*)(st + (size_t)b * HIDDEN + h0);
    float4 c = {0.f, 0.f, 0.f, 0.f};
#pragma unroll
    for (int q = 0; q < 4; ++q) {
        float4 v = *(const float4*)(ctp + ((size_t)q * BATCH + b) * HIDDEN + h0);
        c.x += v.x; c.y += v.y; c.z += v.z; c.w += v.w;
    }
    float4 o;
    o.x = be * s.x + (1.f - be) * c.x;
    o.y = be * s.y + (1.f - be) * c.y;
    o.z = be * s.z + (1.f - be) * c.z;
    o.w = be * s.w + (1.f - be) * c.w;
    *(float4*)(chat + (size_t)b * HIDDEN + h0) = o;
}

// ---------------------------------------------------------------------------
extern "C" void kernel_launch(void* const* d_in, const int* in_sizes, int n_in,
                              void* d_out, int out_size, void* d_ws, size_t ws_size,
                              hipStream_t stream) {
    const float* spatial = (const float*)d_in[0];   // (256,196,1024)
    const float* decoder = (const float*)d_in[1];   // (256,1024)
    const float* st      = (const float*)d_in[2];   // (256,1024)
    const float* Wcnn    = (const float*)d_in[3];   // (1024,512)
    const float* Wdec    = (const float*)d_in[4];   // (1024,512)
    const float* Wsen    = (const float*)d_in[5];   // (1024,512)
    const float* Watt    = (const float*)d_in[6];   // (512,1)
    float* out = (float*)d_out;   // alpha[50176] | beta[256] | c_hat[262144]

    char* ws = (char*)d_ws;
    unsigned short* Wt = (unsigned short*)(ws + 0);   // 1 MB B images
    float* zt   = (float*)(ws + 1048576);             // 50176 f32
    float* dec  = (float*)(ws + 1249280);             // 256x512
    float* stw  = (float*)(ws + 1773568);             // 256x512
    float* beta = (float*)(ws + 2297856);             // 256
    float* ctp  = (float*)(ws + 2298880);             // 4x256x1024 partials (4 MB)

    k0_arrange<<<256, 256, 0, stream>>>(Wcnn, Wt);
    k1_small<<<dim3(4, 32, 2), 256, 0, stream>>>(decoder, st, Wdec, Wsen, dec, stw);
    k2_fused<<<MT_TILES, 256, 0, stream>>>(spatial, Wt, dec, Watt, zt);
    k3_softmax<<<256, 256, 0, stream>>>(dec, stw, Watt, zt, out, beta);
    k4_ct<<<dim3(4, 256), 256, 0, stream>>>(spatial, out, ctp);
    k5_chat<<<256, 256, 0, stream>>>(st, ctp, beta, out + M_TOTAL + BATCH);
}

// Round 11
// 248.587 us; speedup vs baseline: 1.1232x; 1.1232x over previous
//
#include <hip/hip_runtime.h>
#include <hip/hip_bf16.h>

// Problem constants
#define BATCH   256
#define NP      196
#define HIDDEN  1024
#define ATT     512
#define M_TOTAL (BATCH * NP)   // 50176 rows
#define BM 128
#define BN 128
#define NB_TILES (ATT / BN)       // 4
#define MT_TILES (M_TOTAL / BM)   // 392

typedef __attribute__((ext_vector_type(8))) short bf16x8v;  // 8 bf16 = 4 VGPR
typedef __attribute__((ext_vector_type(4))) float f32x4;

// f32 -> bf16 RNE (cold path)
__device__ inline unsigned short f2bf(float x) {
    unsigned int u = __float_as_uint(x);
    u += 0x7fffu + ((u >> 16) & 1u);
    return (unsigned short)(u >> 16);
}

// packed f32 pair -> 2x bf16 via v_cvt_pk_bf16_f32 (no builtin on gfx950)
__device__ __forceinline__ unsigned int pk2bf(float lo, float hi) {
    unsigned int r;
    asm("v_cvt_pk_bf16_f32 %0, %1, %2" : "=v"(r) : "v"(lo), "v"(hi));
    return r;
}

__device__ inline float fast_tanh(float x) {
    float e = __expf(2.0f * x);
    return 1.0f - 2.0f / (e + 1.0f);
}

// async global->LDS, 16 bytes per lane.
__device__ __forceinline__ void glds16(const void* gsrc, void* ldst) {
    __builtin_amdgcn_global_load_lds(
        (const __attribute__((address_space(1))) unsigned int*)gsrc,
        (__attribute__((address_space(3))) unsigned int*)ldst,
        16, 0, 0);
}

// ---------------------------------------------------------------------------
// K0: W_cnn (f32 [1024][512]) -> bf16 tiled+slot-swizzled B images.
// Wt[nb 4][kt 32][8KB image]; byte = col*64 + slot*16; phys slot holds
// k-chunk c = slot ^ ((col&7)>>1), k = kt*32 + c*8 + j.   (R9-verified)
// ---------------------------------------------------------------------------
__global__ void k0_arrange(const float* __restrict__ Wc, unsigned short* __restrict__ Wt) {
    int g = blockIdx.x * 256 + threadIdx.x;   // 65536 slots of 8 bf16
    int nb   = g >> 14;
    int kt   = (g >> 9) & 31;
    int col  = (g >> 2) & 127;
    int slot = g & 3;
    int c    = slot ^ ((col & 7) >> 1);
    int kb   = kt * 32 + c * 8;
    int colg = nb * 128 + col;
    unsigned short v[8];
#pragma unroll
    for (int j = 0; j < 8; ++j) v[j] = f2bf(Wc[(size_t)(kb + j) * ATT + colg]);
    uint4 pk;
    pk.x = (unsigned int)v[0] | ((unsigned int)v[1] << 16);
    pk.y = (unsigned int)v[2] | ((unsigned int)v[3] << 16);
    pk.z = (unsigned int)v[4] | ((unsigned int)v[5] << 16);
    pk.w = (unsigned int)v[6] | ((unsigned int)v[7] << 16);
    *(uint4*)(Wt + (size_t)g * 8) = pk;
}

// ---------------------------------------------------------------------------
// K_PRE v2: spatial (f32) -> bf16 A images, byte-identical to R9's layout:
// Ab[mt 392][kt 32][8KB]; byte = row*64 + sphys*16, sphys = slog ^ ((row&7)>>1).
// v2 access pattern: each wave reads 2 KB CONTIGUOUS (lane = one 32 B k-chunk
// of one row); writes are 64 B segments at 8 KB stride (posted, BW-clean).
// ---------------------------------------------------------------------------
__global__ void k_pre(const float* __restrict__ sp, unsigned short* __restrict__ Ab) {
    int g = blockIdx.x * 256 + threadIdx.x;   // 50176 * 128 slots
    int rg   = g >> 7;            // global row
    int c    = g & 127;           // kt*4 + slog
    int kt   = c >> 2;
    int slog = c & 3;
    const float* src = sp + (size_t)rg * HIDDEN + kt * 32 + slog * 8;
    float4 a = ((const float4*)src)[0];
    float4 b = ((const float4*)src)[1];
    uint4 u;
    u.x = pk2bf(a.x, a.y);
    u.y = pk2bf(a.z, a.w);
    u.z = pk2bf(b.x, b.y);
    u.w = pk2bf(b.z, b.w);
    int mt  = rg >> 7;
    int row = rg & 127;
    int sphys = slog ^ ((row & 7) >> 1);
    *(uint4*)((char*)Ab + (size_t)mt * 262144 + kt * 8192 + row * 64 + sphys * 16) = u;
}

// ---------------------------------------------------------------------------
// K1: dec_out = decoder_out @ W_dec ; stw = st @ W_sen   (f32)
// ---------------------------------------------------------------------------
__global__ void k1_small(const float* __restrict__ dec_in, const float* __restrict__ st,
                         const float* __restrict__ Wdec,  const float* __restrict__ Wsen,
                         float* __restrict__ dec_out, float* __restrict__ stw) {
    const float* X = blockIdx.z ? st   : dec_in;
    const float* W = blockIdx.z ? Wsen : Wdec;
    float*       O = blockIdx.z ? stw  : dec_out;
    int ci = threadIdx.x & 31;
    int c0 = blockIdx.x * 128 + ci * 4;
    int b  = blockIdx.y * 8 + (threadIdx.x >> 5);
    const float* x = X + (size_t)b * HIDDEN;
    float4 acc = {0.f, 0.f, 0.f, 0.f};
    for (int k = 0; k < HIDDEN; k += 4) {
#pragma unroll
        for (int kk = 0; kk < 4; ++kk) {
            float4 w = *(const float4*)(W + (size_t)(k + kk) * ATT + c0);
            float a = x[k + kk];
            acc.x += a * w.x; acc.y += a * w.y; acc.z += a * w.z; acc.w += a * w.w;
        }
    }
    *(float4*)(O + (size_t)b * ATT + c0) = acc;
}

// ---------------------------------------------------------------------------
// K2 v2: R9's verified compute (contiguous glds from pre-tiled images, zero
// VALU staging) + R5's verified 3-buffer depth-2 schedule: stage(t+2) each
// iter, counted s_waitcnt vmcnt(4) lgkmcnt(0) (one full iter of latency
// slack; never drains to 0 in the loop), ONE barrier per K-step.
// 128x128 tile, 256 thr / 4 waves (2x2), 48 KB LDS -> 3 blocks/CU.
// ---------------------------------------------------------------------------
__global__ void __launch_bounds__(256, 3)
k2_gemm(const unsigned short* __restrict__ Ab, const unsigned short* __restrict__ Wt,
        const float* __restrict__ dec, const float* __restrict__ Watt,
        float* __restrict__ ztp) {
    __shared__ __align__(16) char lds[3 * 16384];   // buf q: [A 8KB][B 8KB]
    __shared__ float zred[256];

    const int tid = threadIdx.x;
    const int w  = tid >> 6;
    const int l  = tid & 63;
    const int lg = l >> 4, ll = l & 15;
    const int wr = w >> 1, wc = w & 1;       // 2x2 wave grid, wave = 64x64

    // XCD-bijective swizzle: 1568 = 8 x 196; 4 nb-blocks of an mt adjacent
    // within an XCD chunk -> Ab strip + Wt L2 reuse.
    const int bid = (int)blockIdx.x;
    const int swz = (bid & 7) * 196 + (bid >> 3);
    const int mt = swz >> 2, nb = swz & 3;
    const int r0 = mt * BM;
    const int c0 = nb * BN;

    f32x4 acc[4][4];
#pragma unroll
    for (int m = 0; m < 4; ++m)
#pragma unroll
        for (int n = 0; n < 4; ++n) acc[m][n] = (f32x4){0.f, 0.f, 0.f, 0.f};

    const char* aimg = (const char*)Ab + (size_t)mt * 262144;
    const char* bimg = (const char*)Wt + (size_t)nb * 262144;
    const int fx = (ll >> 1) & 3;            // (row&7)>>1 with row ≡ ll (mod 8)

#define STAGE(kt, q) do {                                                      \
    const char* a_ = aimg + (kt) * 8192 + tid * 16;                            \
    const char* b_ = bimg + (kt) * 8192 + tid * 16;                            \
    char* d_ = lds + (q) * 16384;                                              \
    glds16(a_,        d_ +         tid * 16);                                  \
    glds16(a_ + 4096, d_ + 4096  + tid * 16);                                  \
    glds16(b_,        d_ + 8192  + tid * 16);                                  \
    glds16(b_ + 4096, d_ + 12288 + tid * 16);                                  \
} while (0)

#define COMPUTE(q) do {                                                        \
    const char* As = lds + (q) * 16384;                                        \
    const char* Bs = As + 8192;                                                \
    bf16x8v af[4], bfr[4];                                                     \
    _Pragma("unroll")                                                          \
    for (int m = 0; m < 4; ++m)                                                \
        af[m] = *(const bf16x8v*)(As + (wr * 64 + m * 16 + ll) * 64 +          \
                                  ((lg ^ fx) << 4));                           \
    _Pragma("unroll")                                                          \
    for (int n = 0; n < 4; ++n)                                                \
        bfr[n] = *(const bf16x8v*)(Bs + (wc * 64 + n * 16 + ll) * 64 +         \
                                   ((lg ^ fx) << 4));                          \
    _Pragma("unroll")                                                          \
    for (int m = 0; m < 4; ++m)                                                \
        _Pragma("unroll")                                                      \
        for (int n = 0; n < 4; ++n)                                            \
            acc[m][n] = __builtin_amdgcn_mfma_f32_16x16x32_bf16(               \
                af[m], bfr[n], acc[m][n], 0, 0, 0);                            \
} while (0)

#define WAIT4 asm volatile("s_waitcnt vmcnt(4) lgkmcnt(0)" ::: "memory")
#define BAR   __builtin_amdgcn_s_barrier()

    // Prologue: stage tiles 0,1 (8 glds in flight)
    STAGE(0, 0);
    STAGE(1, 1);

    // Main loop: iter t waits stage(t) (vmcnt(4): stage(t+1)'s 4 stay in
    // flight), barrier, issues stage(t+2), computes tile t. Unroll x3 for
    // compile-time buffer indices (rule #20).
    for (int tb = 0; tb < 30; tb += 3) {
        WAIT4; BAR; STAGE(tb + 2, 2); COMPUTE(0);
        WAIT4; BAR; STAGE(tb + 3, 0); COMPUTE(1);
        WAIT4; BAR; STAGE(tb + 4, 1); COMPUTE(2);
    }
    // t=30 (buf 0): stage(31) already issued at t=29.
    WAIT4; BAR; COMPUTE(0);
    // t=31 (buf 1): drain.
    asm volatile("s_waitcnt vmcnt(0) lgkmcnt(0)" ::: "memory");
    BAR;
    COMPUTE(1);

#undef STAGE
#undef COMPUTE
#undef WAIT4
#undef BAR

    // Epilogue: tanh + dec add + Watt dot; reduce the wave's 64 cols per row.
    // C frag layout (m89-verified): row = lg*4 + j, col = ll.
    const int clocal = wc * 64 + ll;
    float watt[4];
#pragma unroll
    for (int n = 0; n < 4; ++n) watt[n] = Watt[c0 + clocal + n * 16];

#pragma unroll
    for (int m = 0; m < 4; ++m) {
#pragma unroll
        for (int j = 0; j < 4; ++j) {
            int rl = wr * 64 + m * 16 + lg * 4 + j;
            int rowg = r0 + rl;
            int b = rowg / NP;
            const float* db = dec + (size_t)b * ATT + c0;
            float s = 0.f;
#pragma unroll
            for (int n = 0; n < 4; ++n)
                s += fast_tanh(acc[m][n][j] + db[clocal + n * 16]) * watt[n];
            s += __shfl_xor(s, 1);
            s += __shfl_xor(s, 2);
            s += __shfl_xor(s, 4);
            s += __shfl_xor(s, 8);
            if (ll == 0) zred[rl * 2 + wc] = s;
        }
    }
    __syncthreads();
    if (tid < 128) {
        float t = zred[tid * 2] + zred[tid * 2 + 1];
        ztp[(size_t)nb * M_TOTAL + r0 + tid] = t;
    }
}

// ---------------------------------------------------------------------------
// K2 fallback (f32-A reg-staged, R7/R9-verified): only if ws can't hold Ab.
// ---------------------------------------------------------------------------
__global__ void __launch_bounds__(256, 3)
k2_fallback(const float* __restrict__ A, const unsigned short* __restrict__ Wt,
            const float* __restrict__ dec, const float* __restrict__ Watt,
            float* __restrict__ ztp) {
    __shared__ __align__(16) char Abuf[2][8192];
    __shared__ __align__(16) char Bbuf[2][8192];
    __shared__ float zred[256];

    const int tid = threadIdx.x;
    const int w  = tid >> 6;
    const int l  = tid & 63;
    const int lg = l >> 4, ll = l & 15;
    const int wr = w >> 1, wc = w & 1;

    const int bid = (int)blockIdx.x;
    const int swz = (bid & 7) * 196 + (bid >> 3);
    const int mt = swz >> 2, nb = swz & 3;
    const int r0 = mt * BM;
    const int c0 = nb * BN;

    f32x4 acc[4][4];
#pragma unroll
    for (int m = 0; m < 4; ++m)
#pragma unroll
        for (int n = 0; n < 4; ++n) acc[m][n] = (f32x4){0.f, 0.f, 0.f, 0.f};

    const float* asrc = A + (size_t)(r0 + (tid >> 3)) * HIDDEN + (tid & 7) * 4;
    const int aw_off = ((tid >> 3) * 64)
                     + (((((tid >> 1) & 3) ^ ((tid >> 4) & 3))) << 4)
                     + ((tid & 1) * 8);
    const char* bimg = (const char*)Wt + (size_t)nb * (32 * 8192) + tid * 16;

    float4 avA[4], avB[4];

#define ALOADN(t, av) do {                                                     \
    _Pragma("unroll")                                                          \
    for (int j = 0; j < 4; ++j)                                                \
        (av)[j] = *(const float4*)(asrc + (size_t)j * 32 * HIDDEN + (t) * 32); \
} while (0)
#define BGLDS(t, buf) do {                                                     \
    glds16(bimg + (size_t)(t) * 8192,        (buf) + tid * 16);                \
    glds16(bimg + (size_t)(t) * 8192 + 4096, (buf) + 4096 + tid * 16);         \
} while (0)
#define AWRITE(av, buf) do {                                                   \
    _Pragma("unroll")                                                          \
    for (int j = 0; j < 4; ++j) {                                              \
        uint2 u;                                                               \
        u.x = pk2bf((av)[j].x, (av)[j].y);                                     \
        u.y = pk2bf((av)[j].z, (av)[j].w);                                     \
        *(uint2*)((buf) + j * 2048 + aw_off) = u;                              \
    }                                                                          \
} while (0)
#define COMPUTE(Ab, Bb) do {                                                   \
    const int fx = (ll >> 1) & 3;                                              \
    bf16x8v af[4], bfr[4];                                                     \
    _Pragma("unroll")                                                          \
    for (int m = 0; m < 4; ++m)                                                \
        af[m] = *(const bf16x8v*)((Ab) + (wr * 64 + m * 16 + ll) * 64 +        \
                                  ((lg ^ fx) << 4));                           \
    _Pragma("unroll")                                                          \
    for (int n = 0; n < 4; ++n)                                                \
        bfr[n] = *(const bf16x8v*)((Bb) + (wc * 64 + n * 16 + ll) * 64 +       \
                                   ((lg ^ fx) << 4));                          \
    _Pragma("unroll")                                                          \
    for (int m = 0; m < 4; ++m)                                                \
        _Pragma("unroll")                                                      \
        for (int n = 0; n < 4; ++n)                                            \
            acc[m][n] = __builtin_amdgcn_mfma_f32_16x16x32_bf16(               \
                af[m], bfr[n], acc[m][n], 0, 0, 0);                            \
} while (0)
#define WAITC asm volatile("s_waitcnt vmcnt(4) lgkmcnt(0)" ::: "memory")
#define BAR   __builtin_amdgcn_s_barrier()

    BGLDS(0, Bbuf[0]);
    ALOADN(0, avA);
    ALOADN(1, avB);
    AWRITE(avA, Abuf[0]);
    WAITC;
    BAR;

    for (int tp = 0; tp < 15; ++tp) {
        const int t = tp * 2;
        BGLDS(t + 1, Bbuf[1]);
        ALOADN(t + 2, avA);
        COMPUTE(Abuf[0], Bbuf[0]);
        AWRITE(avB, Abuf[1]);
        WAITC; BAR;
        BGLDS(t + 2, Bbuf[0]);
        ALOADN((t + 3 > 31 ? 31 : t + 3), avB);
        COMPUTE(Abuf[1], Bbuf[1]);
        AWRITE(avA, Abuf[0]);
        WAITC; BAR;
    }
    BGLDS(31, Bbuf[1]);
    COMPUTE(Abuf[0], Bbuf[0]);
    AWRITE(avB, Abuf[1]);
    asm volatile("s_waitcnt vmcnt(0) lgkmcnt(0)" ::: "memory");
    BAR;
    COMPUTE(Abuf[1], Bbuf[1]);

#undef ALOADN
#undef BGLDS
#undef AWRITE
#undef COMPUTE
#undef WAITC
#undef BAR

    const int clocal = wc * 64 + ll;
    float watt[4];
#pragma unroll
    for (int n = 0; n < 4; ++n) watt[n] = Watt[c0 + clocal + n * 16];

#pragma unroll
    for (int m = 0; m < 4; ++m) {
#pragma unroll
        for (int j = 0; j < 4; ++j) {
            int rl = wr * 64 + m * 16 + lg * 4 + j;
            int rowg = r0 + rl;
            int b = rowg / NP;
            const float* db = dec + (size_t)b * ATT + c0;
            float s = 0.f;
#pragma unroll
            for (int n = 0; n < 4; ++n)
                s += fast_tanh(acc[m][n][j] + db[clocal + n * 16]) * watt[n];
            s += __shfl_xor(s, 1);
            s += __shfl_xor(s, 2);
            s += __shfl_xor(s, 4);
            s += __shfl_xor(s, 8);
            if (ll == 0) zred[rl * 2 + wc] = s;
        }
    }
    __syncthreads();
    if (tid < 128) {
        float t = zred[tid * 2] + zred[tid * 2 + 1];
        ztp[(size_t)nb * M_TOTAL + r0 + tid] = t;
    }
}

// ---------------------------------------------------------------------------
// K3: per-b: out = tanh(dec+stw)@Watt ; alpha = softmax(zt) ; beta.
// ---------------------------------------------------------------------------
__global__ void k3_softmax(const float* __restrict__ dec, const float* __restrict__ stw,
                           const float* __restrict__ Watt, const float* __restrict__ ztp,
                           float* __restrict__ out, float* __restrict__ beta_ws) {
    int b = blockIdx.x;
    int t = threadIdx.x;
    __shared__ float red[256];

    float p = 0.f;
#pragma unroll
    for (int c = t; c < ATT; c += 256)
        p += fast_tanh(dec[(size_t)b * ATT + c] + stw[(size_t)b * ATT + c]) * Watt[c];
    red[t] = p;
    __syncthreads();
    for (int s = 128; s > 0; s >>= 1) { if (t < s) red[t] += red[t + s]; __syncthreads(); }
    float outv = red[0];
    __syncthreads();

    float z = -1e30f;
    if (t < NP) {
        z = ztp[b * NP + t] + ztp[M_TOTAL + b * NP + t]
          + ztp[2 * M_TOTAL + b * NP + t] + ztp[3 * M_TOTAL + b * NP + t];
    }
    red[t] = z;
    __syncthreads();
    for (int s = 128; s > 0; s >>= 1) { if (t < s) red[t] = fmaxf(red[t], red[t + s]); __syncthreads(); }
    float m1 = red[0];
    __syncthreads();

    float e = (t < NP) ? __expf(z - m1) : 0.f;
    red[t] = e;
    __syncthreads();
    for (int s = 128; s > 0; s >>= 1) { if (t < s) red[t] += red[t + s]; __syncthreads(); }
    float s1 = red[0];

    if (t < NP) out[b * NP + t] = e / s1;                       // alpha_t

    if (t == 0) {
        float m2 = fmaxf(m1, outv);
        float s2 = s1 * __expf(m1 - m2) + __expf(outv - m2);
        float beta = __expf(outv - m2) / s2;
        out[M_TOTAL + b] = beta;                                 // beta_t
        beta_ws[b] = beta;
    }
}

// ---------------------------------------------------------------------------
// K4: ct partials. grid (4 p-quarters, 256 b), block 256 (thread = 4 h).
// ---------------------------------------------------------------------------
__global__ void k4_ct(const float* __restrict__ spatial, const float* __restrict__ alpha,
                      float* __restrict__ ctp) {
    int q = blockIdx.x;
    int b = blockIdx.y;
    int t = threadIdx.x;
    __shared__ float al[49];
    if (t < 49) al[t] = alpha[b * NP + q * 49 + t];
    __syncthreads();
    const float* sp = spatial + (size_t)b * NP * HIDDEN + (size_t)q * 49 * HIDDEN + t * 4;
    float4 acc = {0.f, 0.f, 0.f, 0.f};
#pragma unroll 7
    for (int p = 0; p < 49; ++p) {
        float4 v = *(const float4*)(sp + (size_t)p * HIDDEN);
        float a = al[p];
        acc.x += a * v.x; acc.y += a * v.y; acc.z += a * v.z; acc.w += a * v.w;
    }
    *(float4*)(ctp + ((size_t)q * BATCH + b) * HIDDEN + t * 4) = acc;
}

// ---------------------------------------------------------------------------
// K5: c_hat = beta*st + (1-beta)*ct  (sums the 4 ct partials)
// ---------------------------------------------------------------------------
__global__ void k5_chat(const float* __restrict__ st, const float* __restrict__ ctp,
                        const float* __restrict__ beta, float* __restrict__ chat) {
    int g = blockIdx.x * 256 + threadIdx.x;
    int b = g >> 8;
    int h0 = (g & 255) * 4;
    float be = beta[b];
    float4 s = *(const float4*)(st + (size_t)b * HIDDEN + h0);
    float4 c = {0.f, 0.f, 0.f, 0.f};
#pragma unroll
    for (int q = 0; q < 4; ++q) {
        float4 v = *(const float4*)(ctp + ((size_t)q * BATCH + b) * HIDDEN + h0);
        c.x += v.x; c.y += v.y; c.z += v.z; c.w += v.w;
    }
    float4 o;
    o.x = be * s.x + (1.f - be) * c.x;
    o.y = be * s.y + (1.f - be) * c.y;
    o.z = be * s.z + (1.f - be) * c.z;
    o.w = be * s.w + (1.f - be) * c.w;
    *(float4*)(chat + (size_t)b * HIDDEN + h0) = o;
}

// ---------------------------------------------------------------------------
extern "C" void kernel_launch(void* const* d_in, const int* in_sizes, int n_in,
                              void* d_out, int out_size, void* d_ws, size_t ws_size,
                              hipStream_t stream) {
    const float* spatial = (const float*)d_in[0];   // (256,196,1024)
    const float* decoder = (const float*)d_in[1];   // (256,1024)
    const float* st      = (const float*)d_in[2];   // (256,1024)
    const float* Wcnn    = (const float*)d_in[3];   // (1024,512)
    const float* Wdec    = (const float*)d_in[4];   // (1024,512)
    const float* Wsen    = (const float*)d_in[5];   // (1024,512)
    const float* Watt    = (const float*)d_in[6];   // (512,1)
    float* out = (float*)d_out;   // alpha[50176] | beta[256] | c_hat[262144]

    const size_t AB_BYTES   = (size_t)MT_TILES * 32 * 8192;   // 102,760,448
    const size_t SMALL_NEED = 1048576 + 802816 + 524288 + 524288 + 1024 + 4194304;
    const int use_pre = (ws_size >= AB_BYTES + SMALL_NEED);

    char* ws = (char*)d_ws;
    size_t off = use_pre ? AB_BYTES : 0;
    unsigned short* Ab = (unsigned short*)ws;                 // primary only
    unsigned short* Wt = (unsigned short*)(ws + off); off += 1048576;
    float* ztp  = (float*)(ws + off); off += 802816;          // 4 x 50176
    float* dec  = (float*)(ws + off); off += 524288;
    float* stw  = (float*)(ws + off); off += 524288;
    float* beta = (float*)(ws + off); off += 1024;
    float* ctp  = (float*)(ws + off);                         // 4 MB

    k0_arrange<<<256, 256, 0, stream>>>(Wcnn, Wt);
    k1_small<<<dim3(4, 32, 2), 256, 0, stream>>>(decoder, st, Wdec, Wsen, dec, stw);
    if (use_pre) {
        k_pre<<<25088, 256, 0, stream>>>(spatial, Ab);
        k2_gemm<<<MT_TILES * NB_TILES, 256, 0, stream>>>(Ab, Wt, dec, Watt, ztp);
    } else {
        k2_fallback<<<MT_TILES * NB_TILES, 256, 0, stream>>>(spatial, Wt, dec, Watt, ztp);
    }
    k3_softmax<<<256, 256, 0, stream>>>(dec, stw, Watt, ztp, out, beta);
    k4_ct<<<dim3(4, 256), 256, 0, stream>>>(spatial, out, ctp);
    k5_chat<<<256, 256, 0, stream>>>(st, ctp, beta, out + M_TOTAL + BATCH);
}